// Round 5
// baseline (473.596 us; speedup 1.0000x reference)
//
#include <hip/hip_runtime.h>

// Problem constants
#define N_ 64
#define H_ 256
#define W_ 256
#define C_ 16
#define O_ 16

// Wave-streaming config: block = ONE wave (64 lanes), lane = column of a
// 64-wide strip; block slides over CH rows. NO __syncthreads anywhere:
// the +/-1 column halo exchange is intra-wave via LDS (same-wave DS ops are
// program-ordered; compiler inserts lgkmcnt only). No barrier => no
// vmcnt(0) drain => row r+1's global loads overlap row r's compute.
#define SW 64
#define CH 16
#define NCOL 66   // 64 cols + 2 halo cols in LDS

// LDS: 4 channel-planes x 66 cols of float4 = 4,224 B, SINGLE slot (same-wave
// write->read->overwrite is safe in program order). Plane-major, lane-stride-1
// granules => conflict-free b128 writes and +/-1 tap reads.

__global__ __launch_bounds__(64, 3)
void sep_conv_kernel(const float* __restrict__ in,
                     const float* __restrict__ u,   // (O,K) = (16,3)
                     const float* __restrict__ v,   // (O,K)
                     const float* __restrict__ w,   // (O,C) = (16,16)
                     const float* __restrict__ b,   // (O)
                     float* __restrict__ out) {
    __shared__ float4 t_lds[4 * NCOL];

    const int lane = threadIdx.x;              // 0..63 = strip column
    const int x0   = blockIdx.x * SW;
    const int y0   = blockIdx.y * CH;
    const int n    = blockIdx.z;
    const int gx   = x0 + lane;

    const float* inb  = in  + (size_t)n * H_ * W_ * C_;
    float*       outb = out + (size_t)n * H_ * W_ * C_;   // O_ == C_

    // ---- halo assignment: lanes 0..15 -> left col (x0-1), 16..31 -> right
    // (x0+64); each halo lane computes ONE channel (hl) of halo-t via a
    // 16-FMA dot with its private weight row wh (loaded once, 16 VGPRs).
    const int  which = (lane >> 4) & 1;
    const int  hl    = lane & 15;
    const int  hx    = which ? (x0 + SW) : (x0 - 1);
    const bool hval  = (unsigned)hx < (unsigned)W_;   // SAME padding -> 0 outside

    float4 wh4[4];
    {
        const float4* s4 = (const float4*)(w + hl * 16);
        #pragma unroll
        for (int q = 0; q < 4; ++q) wh4[q] = s4[q];
    }

    float4 pf[4], xh[4];
    float  tn[16], th;
    float  hp[16], hc[16], hn[16];
    #pragma unroll
    for (int q = 0; q < 4; ++q) xh[q] = make_float4(0.f, 0.f, 0.f, 0.f);

#define LOAD_MAIN(r) {                                                         \
    const float4* s4_ = (const float4*)(inb + ((size_t)(r) * W_ + gx) * C_);   \
    pf[0] = s4_[0]; pf[1] = s4_[1]; pf[2] = s4_[2]; pf[3] = s4_[3]; }

#define LOAD_HALO(r) {                                                         \
    if (hval) {                                                                \
        const float4* s4_ = (const float4*)(inb + ((size_t)(r) * W_ + hx) * C_);\
        xh[0] = s4_[0]; xh[1] = s4_[1]; xh[2] = s4_[2]; xh[3] = s4_[3]; } }

#define CMIX_MAIN() {                                                          \
    const float iv_[16] = {pf[0].x, pf[0].y, pf[0].z, pf[0].w,                 \
                           pf[1].x, pf[1].y, pf[1].z, pf[1].w,                 \
                           pf[2].x, pf[2].y, pf[2].z, pf[2].w,                 \
                           pf[3].x, pf[3].y, pf[3].z, pf[3].w};                \
    _Pragma("unroll")                                                          \
    for (int l = 0; l < 16; ++l) {                                             \
        float s_ = 0.f;                                                        \
        _Pragma("unroll")                                                      \
        for (int k = 0; k < 16; ++k) s_ = fmaf(w[l * 16 + k], iv_[k], s_);     \
        tn[l] = s_;                                                            \
    } }

#define CMIX_HALO() {                                                          \
    const float whf_[16] = {wh4[0].x, wh4[0].y, wh4[0].z, wh4[0].w,            \
                            wh4[1].x, wh4[1].y, wh4[1].z, wh4[1].w,            \
                            wh4[2].x, wh4[2].y, wh4[2].z, wh4[2].w,            \
                            wh4[3].x, wh4[3].y, wh4[3].z, wh4[3].w};           \
    const float xhf_[16] = {xh[0].x, xh[0].y, xh[0].z, xh[0].w,                \
                            xh[1].x, xh[1].y, xh[1].z, xh[1].w,                \
                            xh[2].x, xh[2].y, xh[2].z, xh[2].w,                \
                            xh[3].x, xh[3].y, xh[3].z, xh[3].w};               \
    th = 0.f;                                                                  \
    _Pragma("unroll")                                                          \
    for (int k = 0; k < 16; ++k) th = fmaf(whf_[k], xhf_[k], th); }

// write t (+halo) to LDS, read +/-1 taps, horizontal 3-tap into hdst.
// Same-wave LDS: compiler's lgkmcnt waits are sufficient, no barrier.
#define EXCHANGE_AND_H(hdst) {                                                 \
    t_lds[0 * NCOL + lane + 1] = make_float4(tn[0],  tn[1],  tn[2],  tn[3]);   \
    t_lds[1 * NCOL + lane + 1] = make_float4(tn[4],  tn[5],  tn[6],  tn[7]);   \
    t_lds[2 * NCOL + lane + 1] = make_float4(tn[8],  tn[9],  tn[10], tn[11]);  \
    t_lds[3 * NCOL + lane + 1] = make_float4(tn[12], tn[13], tn[14], tn[15]);  \
    if (lane < 32) {                                                           \
        ((float*)t_lds)[((hl >> 2) * NCOL + (which ? (NCOL - 1) : 0)) * 4 +    \
                        (hl & 3)] = th;                                        \
    }                                                                          \
    float4 m4_[4], p4_[4];                                                     \
    _Pragma("unroll")                                                          \
    for (int q = 0; q < 4; ++q) {                                              \
        m4_[q] = t_lds[q * NCOL + lane];                                       \
        p4_[q] = t_lds[q * NCOL + lane + 2];                                   \
    }                                                                          \
    const float tm_[16] = {m4_[0].x, m4_[0].y, m4_[0].z, m4_[0].w,             \
                           m4_[1].x, m4_[1].y, m4_[1].z, m4_[1].w,             \
                           m4_[2].x, m4_[2].y, m4_[2].z, m4_[2].w,             \
                           m4_[3].x, m4_[3].y, m4_[3].z, m4_[3].w};            \
    const float tp_[16] = {p4_[0].x, p4_[0].y, p4_[0].z, p4_[0].w,             \
                           p4_[1].x, p4_[1].y, p4_[1].z, p4_[1].w,             \
                           p4_[2].x, p4_[2].y, p4_[2].z, p4_[2].w,             \
                           p4_[3].x, p4_[3].y, p4_[3].z, p4_[3].w};            \
    _Pragma("unroll")                                                          \
    for (int l = 0; l < 16; ++l)                                               \
        hdst[l] = fmaf(u[l * 3 + 0], tm_[l],                                   \
                  fmaf(u[l * 3 + 2], tp_[l], u[l * 3 + 1] * tn[l])); }

// produce h(row) from already-loaded pf/xh; optionally reissue pf/xh loads
// for r_next mid-step so they complete under the LDS+hrow+epilogue work.
#define PRODUCE(hdst, r_next, do_pref) {                                       \
    CMIX_MAIN();                                                               \
    if (do_pref) LOAD_MAIN(r_next);                                            \
    CMIX_HALO();                                                               \
    if (do_pref) LOAD_HALO(r_next);                                            \
    EXCHANGE_AND_H(hdst); }

    // ---- warmup: h(y0-1) -> hp, h(y0) -> hc ----
    if (y0 > 0) {
        LOAD_MAIN(y0 - 1);
        LOAD_HALO(y0 - 1);
        PRODUCE(hp, y0, true);            // produce h(y0-1), prefetch row y0
    } else {
        #pragma unroll
        for (int l = 0; l < 16; ++l) hp[l] = 0.f;
        LOAD_MAIN(y0);
        LOAD_HALO(y0);
    }
    PRODUCE(hc, y0 + 1, true);            // produce h(y0), prefetch y0+1 (<=241)

    // ---- steady state: one output row per iteration, zero barriers ----
    for (int yy = 0; yy < CH; ++yy) {
        const int y  = y0 + yy;
        const int rn = y + 1;             // row whose t/h we produce now
        if (rn < H_) {                    // uniform across the wave
            const int  rnext = rn + 1;
            const bool pref  = (yy + 1 < CH) && (rnext < H_);
            PRODUCE(hn, rnext, pref);
        } else {
            #pragma unroll
            for (int l = 0; l < 16; ++l) hn[l] = 0.f;
        }

        // out[y] = relu(b + v0*h[y-1] + v1*h[y] + v2*h[y+1])
        float r[16];
        #pragma unroll
        for (int l = 0; l < 16; ++l) {
            float val = fmaf(v[l * 3 + 0], hp[l],
                        fmaf(v[l * 3 + 1], hc[l],
                        fmaf(v[l * 3 + 2], hn[l], b[l])));
            r[l] = fmaxf(val, 0.f);
        }
        float4* o4 = (float4*)(outb + ((size_t)y * W_ + gx) * C_);
        o4[0] = make_float4(r[0],  r[1],  r[2],  r[3]);
        o4[1] = make_float4(r[4],  r[5],  r[6],  r[7]);
        o4[2] = make_float4(r[8],  r[9],  r[10], r[11]);
        o4[3] = make_float4(r[12], r[13], r[14], r[15]);

        #pragma unroll
        for (int l = 0; l < 16; ++l) { hp[l] = hc[l]; hc[l] = hn[l]; }
    }

#undef LOAD_MAIN
#undef LOAD_HALO
#undef CMIX_MAIN
#undef CMIX_HALO
#undef EXCHANGE_AND_H
#undef PRODUCE
}

extern "C" void kernel_launch(void* const* d_in, const int* in_sizes, int n_in,
                              void* d_out, int out_size, void* d_ws, size_t ws_size,
                              hipStream_t stream) {
    const float* in = (const float*)d_in[0];
    const float* u  = (const float*)d_in[1];
    const float* v  = (const float*)d_in[2];
    const float* w  = (const float*)d_in[3];
    const float* b  = (const float*)d_in[4];
    float* out = (float*)d_out;

    dim3 grid(W_ / SW, H_ / CH, N_);   // 4 x 16 x 64 = 4096 single-wave blocks
    dim3 block(SW);                    // 64 threads = 1 wave
    sep_conv_kernel<<<grid, block, 0, stream>>>(in, u, v, w, b, out);
}